// Round 1
// baseline (444.513 us; speedup 1.0000x reference)
//
#include <hip/hip_runtime.h>
#include <math.h>

#define BB 4
#define LL 512
#define DD 256
#define HH 8
#define DHH 32
#define NB 12  // BUCKETS + 1 (row 11 is the zero padding row)

// K1: QKV projections (8-row tiles, 768 blocks = 3 blocks/CU).
// Thread = 2 rows x 4 cols. mat0 writes Qu=q/sqrt(dh)+u, Qv=q/sqrt(dh)+v;
// mat1 writes KT[b][h][d][k]; mat2 writes V[b][k][d].
__global__ __launch_bounds__(256) void qkv_kernel(const float* __restrict__ x,
    const float* __restrict__ Wq, const float* __restrict__ bq,
    const float* __restrict__ Wk, const float* __restrict__ bk,
    const float* __restrict__ Wv, const float* __restrict__ bv,
    const float* __restrict__ uvec, const float* __restrict__ vvec,
    float* __restrict__ Qu, float* __restrict__ Qv,
    float* __restrict__ KT, float* __restrict__ V) {
    __shared__ float xs[8][DD];
    const int mat = blockIdx.x >> 8;          // 0=Q, 1=K, 2=V
    const int r0 = (blockIdx.x & 255) * 8;
    const int t = threadIdx.x;
    const int cg = t & 63, rg = t >> 6;
    const int c0 = cg * 4;
    {
        const float4* xg = (const float4*)(x + r0 * DD);
        float4* xsv = (float4*)&xs[0][0];
        xsv[t] = xg[t];
        xsv[t + 256] = xg[t + 256];
    }
    __syncthreads();
    const float* W    = (mat == 0) ? Wq : (mat == 1) ? Wk : Wv;
    const float* bias = (mat == 0) ? bq : (mat == 1) ? bk : bv;
    float acc[2][4];
#pragma unroll
    for (int r = 0; r < 2; ++r)
#pragma unroll
        for (int c = 0; c < 4; ++c) acc[r][c] = bias[c0 + c];
    for (int i0 = 0; i0 < DD; i0 += 4) {
        float4 wv4[4], xv4[2];
#pragma unroll
        for (int j = 0; j < 4; ++j) wv4[j] = *(const float4*)&W[(i0 + j) * DD + c0];
#pragma unroll
        for (int r = 0; r < 2; ++r) xv4[r] = *(const float4*)&xs[rg * 2 + r][i0];
        const float* wf = (const float*)wv4;
        const float* xf = (const float*)xv4;
#pragma unroll
        for (int r = 0; r < 2; ++r)
#pragma unroll
            for (int j = 0; j < 4; ++j)
#pragma unroll
                for (int c = 0; c < 4; ++c)
                    acc[r][c] = fmaf(xf[r * 4 + j], wf[j * 4 + c], acc[r][c]);
    }
    if (mat == 0) {
        const float s = 0.17677669529663687f;  // 1/sqrt(DH)
        const float4 u4 = *(const float4*)&uvec[c0];
        const float4 v4 = *(const float4*)&vvec[c0];
#pragma unroll
        for (int r = 0; r < 2; ++r) {
            const int row = r0 + rg * 2 + r;
            float4 q = make_float4(acc[r][0] * s, acc[r][1] * s, acc[r][2] * s, acc[r][3] * s);
            *(float4*)&Qu[row * DD + c0] = make_float4(q.x + u4.x, q.y + u4.y, q.z + u4.z, q.w + u4.w);
            *(float4*)&Qv[row * DD + c0] = make_float4(q.x + v4.x, q.y + v4.y, q.z + v4.z, q.w + v4.w);
        }
    } else if (mat == 1) {
        const int b = r0 >> 9;
        const int kb = (r0 & 511) + rg * 2;
#pragma unroll
        for (int c = 0; c < 4; ++c) {
            const int col = c0 + c;
            const int h = col >> 5, dd = col & 31;
            float* p = KT + ((long)((b * HH + h) * DHH + dd)) * LL + kb;
            p[0] = acc[0][c];
            p[1] = acc[1][c];
        }
    } else {
#pragma unroll
        for (int r = 0; r < 2; ++r)
            *(float4*)&V[(r0 + rg * 2 + r) * DD + c0] =
                make_float4(acc[r][0], acc[r][1], acc[r][2], acc[r][3]);
    }
}

// K2: fused rel-P + scores + softmax + attn write + ctx.
// Phase A: wave w owns q rows {2w,2w+1}; Q fragments hoisted out of the k-half
// loop (halves Qs LDS reads); scores for both k-halves accumulate in regs.
// S tile in LDS is octet-XOR-swizzled: row q, chunk c, octet o lives at
// ss[q*512 + c*128 + ((o^q)*8 | h4)]. Phase-B reads 4 q-rows per instruction;
// q-stride 512 is bank-invariant (512%32==0), so the XOR spreads the 4 rows
// over 4 distinct bank quads -> conflict-free with NO per-chunk padding.
// Phase B: thread = (qt,dt,kg) = 4 q-tiles x 8 d-tiles x 16 k-octets; each
// thread computes a 4q x 4d register tile over its 8-k octet per chunk:
// 16 ds_read_b128 feed 128 FMA (was 2 reads per 4 FMA -> 4x less LDS read
// traffic; this kernel was LDS-pipe-bound: 256 b128/thread * 12cy ~= 41us).
// kg-partials reduced via LDS reusing the dead ss region (4 b128 writes +
// 16 b32 reads per thread, all bank-uniform).
__global__ __launch_bounds__(512, 4) void scores_ctx_kernel(const float* __restrict__ Qu,
    const float* __restrict__ Qv, const float* __restrict__ KT,
    const float* __restrict__ rel_table, const int* __restrict__ mask,
    const int* __restrict__ dist, const float* __restrict__ V,
    float* __restrict__ attn, float* __restrict__ ctx) {
    __shared__ float Qs[16][DHH];
    __shared__ float Ps[16][NB];
    __shared__ float ss[16 * 512];      // swizzled S tile (32KB); preamble aliases Qv8/rels; epilogue aliases partials
    __shared__ float Vs[DHH][133];      // V chunk, transposed [d][k] (+pad 133: gcd(5,32)=1)
    const int blk = blockIdx.x;         // ((b*32 + qt16)*8 + h)
    const int h = blk & 7;
    const int rest = blk >> 3;
    const int qt16 = rest & 31;
    const int b = rest >> 5;
    const int q0 = qt16 * 16;
    const int t = threadIdx.x;
    const int w = t >> 6, l = t & 63;

    float* Qv8  = ss;                   // [16][32]  (dead after Ps compute)
    float* rels = ss + 512;             // [12][33]  (dead after Ps compute)

    {
        const int r = t >> 5, c = t & 31;
        Qs[r][c]          = Qu[(b * LL + q0 + r) * DD + h * DHH + c];
        Qv8[r * DHH + c]  = Qv[(b * LL + q0 + r) * DD + h * DHH + c];
    }
    if (t < NB * DHH) {
        rels[(t >> 5) * 33 + (t & 31)] = rel_table[(t >> 5) * DD + h * DHH + (t & 31)];
    }
    __syncthreads();
    if (t < 16 * NB) {                  // Ps[r][bk] = dot32(Qv8[r], rels[bk])
        const int bk = t >> 4, r = t & 15;
        float a = 0.f;
#pragma unroll
        for (int d = 0; d < DHH; ++d) a = fmaf(Qv8[r * DHH + d], rels[bk * 33 + d], a);
        Ps[r][bk] = a;
    }
    __syncthreads();                    // after this barrier Qv8/rels are dead; ss is writable

    // ---- Phase A: scores + softmax for this wave's 2 q rows ----
    const int r0 = 2 * w;
    const long kbase = (long)(b * HH + h) * DHH * LL;
    float sc[2][2][4];                  // [row][k-half][k4] scores (init = rel-P term)
#pragma unroll
    for (int s = 0; s < 2; ++s) {
        const int k0 = 4 * l + 256 * s;
        const int4 dx0 = *(const int4*)&dist[(b * LL + q0 + r0) * LL + k0];
        const int4 dx1 = *(const int4*)&dist[(b * LL + q0 + r0 + 1) * LL + k0];
        sc[0][s][0] = Ps[r0][dx0.x];     sc[0][s][1] = Ps[r0][dx0.y];
        sc[0][s][2] = Ps[r0][dx0.z];     sc[0][s][3] = Ps[r0][dx0.w];
        sc[1][s][0] = Ps[r0 + 1][dx1.x]; sc[1][s][1] = Ps[r0 + 1][dx1.y];
        sc[1][s][2] = Ps[r0 + 1][dx1.z]; sc[1][s][3] = Ps[r0 + 1][dx1.w];
    }
#pragma unroll
    for (int d8 = 0; d8 < DHH; d8 += 8) {
        const float4 q0a = *(const float4*)&Qs[r0][d8];      // hoisted: loaded once
        const float4 q0b = *(const float4*)&Qs[r0][d8 + 4];  // for both k-halves
        const float4 q1a = *(const float4*)&Qs[r0 + 1][d8];
        const float4 q1b = *(const float4*)&Qs[r0 + 1][d8 + 4];
        const float* qa0 = (const float*)&q0a;
        const float* qb0 = (const float*)&q0b;
        const float* qa1 = (const float*)&q1a;
        const float* qb1 = (const float*)&q1b;
#pragma unroll
        for (int s = 0; s < 2; ++s) {
            const int k0 = 4 * l + 256 * s;
            float4 kv[8];                        // 8 loads in flight
#pragma unroll
            for (int j = 0; j < 8; ++j)
                kv[j] = *(const float4*)&KT[kbase + (long)(d8 + j) * LL + k0];
#pragma unroll
            for (int j = 0; j < 4; ++j) {
                sc[0][s][0] = fmaf(qa0[j], kv[j].x, sc[0][s][0]);
                sc[0][s][1] = fmaf(qa0[j], kv[j].y, sc[0][s][1]);
                sc[0][s][2] = fmaf(qa0[j], kv[j].z, sc[0][s][2]);
                sc[0][s][3] = fmaf(qa0[j], kv[j].w, sc[0][s][3]);
                sc[1][s][0] = fmaf(qa1[j], kv[j].x, sc[1][s][0]);
                sc[1][s][1] = fmaf(qa1[j], kv[j].y, sc[1][s][1]);
                sc[1][s][2] = fmaf(qa1[j], kv[j].z, sc[1][s][2]);
                sc[1][s][3] = fmaf(qa1[j], kv[j].w, sc[1][s][3]);
            }
#pragma unroll
            for (int j = 0; j < 4; ++j) {
                sc[0][s][0] = fmaf(qb0[j], kv[j + 4].x, sc[0][s][0]);
                sc[0][s][1] = fmaf(qb0[j], kv[j + 4].y, sc[0][s][1]);
                sc[0][s][2] = fmaf(qb0[j], kv[j + 4].z, sc[0][s][2]);
                sc[0][s][3] = fmaf(qb0[j], kv[j + 4].w, sc[0][s][3]);
                sc[1][s][0] = fmaf(qb1[j], kv[j + 4].x, sc[1][s][0]);
                sc[1][s][1] = fmaf(qb1[j], kv[j + 4].y, sc[1][s][1]);
                sc[1][s][2] = fmaf(qb1[j], kv[j + 4].z, sc[1][s][2]);
                sc[1][s][3] = fmaf(qb1[j], kv[j + 4].w, sc[1][s][3]);
            }
        }
    }
    float e0[2][4], e1[2][4];
    float sum0 = 0.f, sum1 = 0.f;
#pragma unroll
    for (int s = 0; s < 2; ++s) {
        const int k0 = 4 * l + 256 * s;
        const int4 mx0 = *(const int4*)&mask[(b * LL + q0 + r0) * LL + k0];
        const int4 mx1 = *(const int4*)&mask[(b * LL + q0 + r0 + 1) * LL + k0];
        e0[s][0] = mx0.x ? 0.f : __expf(sc[0][s][0]);
        e0[s][1] = mx0.y ? 0.f : __expf(sc[0][s][1]);
        e0[s][2] = mx0.z ? 0.f : __expf(sc[0][s][2]);
        e0[s][3] = mx0.w ? 0.f : __expf(sc[0][s][3]);
        e1[s][0] = mx1.x ? 0.f : __expf(sc[1][s][0]);
        e1[s][1] = mx1.y ? 0.f : __expf(sc[1][s][1]);
        e1[s][2] = mx1.z ? 0.f : __expf(sc[1][s][2]);
        e1[s][3] = mx1.w ? 0.f : __expf(sc[1][s][3]);
        sum0 += (e0[s][0] + e0[s][1]) + (e0[s][2] + e0[s][3]);
        sum1 += (e1[s][0] + e1[s][1]) + (e1[s][2] + e1[s][3]);
    }
    for (int off = 32; off > 0; off >>= 1) {
        sum0 += __shfl_xor(sum0, off);
        sum1 += __shfl_xor(sum1, off);
    }
    const float inv0 = 1.0f / sum0, inv1 = 1.0f / sum1;
    float* a0 = attn + ((long)(b * HH + h) * LL + q0 + r0) * LL;
    float* a1 = a0 + LL;
#pragma unroll
    for (int s = 0; s < 2; ++s) {
        const int k0 = 4 * l + 256 * s;
        const int ch = k0 >> 7;
        const int oct = (k0 & 127) >> 3;
        const int h4 = k0 & 4;
        const float4 o0 = make_float4(e0[s][0] * inv0, e0[s][1] * inv0, e0[s][2] * inv0, e0[s][3] * inv0);
        const float4 o1 = make_float4(e1[s][0] * inv1, e1[s][1] * inv1, e1[s][2] * inv1, e1[s][3] * inv1);
        *(float4*)&a0[k0] = o0;
        *(float4*)&a1[k0] = o1;
        *(float4*)&ss[r0 * 512 + ch * 128 + (((oct ^ r0) << 3) | h4)] = o0;
        *(float4*)&ss[(r0 + 1) * 512 + ch * 128 + (((oct ^ (r0 + 1)) << 3) | h4)] = o1;
    }

    // ---- Phase B: ctx via 4q x 4d register tiles over LDS-staged V chunks ----
    const int qt = t & 3;               // q-tile (rows 4qt..4qt+3)
    const int dt = (t >> 2) & 7;        // d-tile (cols 4dt..4dt+3)
    const int kg = t >> 5;              // k-octet within chunk (0..15)
    const int kkS = t >> 2;             // staging row 0..127
    const int dqS = (t & 3) * 8;        // staging d-group of 8
    float acc[4][4];
#pragma unroll
    for (int i = 0; i < 4; ++i)
#pragma unroll
        for (int jd = 0; jd < 4; ++jd) acc[i][jd] = 0.f;
    for (int c = 0; c < 4; ++c) {
        __syncthreads();                // prev compute done (and ss ready at c=0)
        {   // stage V[b][c*128+kk][h*32+dq..dq+7] -> Vs[d][kk] (transposed)
            const float* vg = V + ((long)(b * LL + c * 128 + kkS)) * DD + h * DHH + dqS;
            const float4 va = *(const float4*)&vg[0];
            const float4 vb4 = *(const float4*)&vg[4];
            Vs[dqS + 0][kkS] = va.x;  Vs[dqS + 1][kkS] = va.y;
            Vs[dqS + 2][kkS] = va.z;  Vs[dqS + 3][kkS] = va.w;
            Vs[dqS + 4][kkS] = vb4.x; Vs[dqS + 5][kkS] = vb4.y;
            Vs[dqS + 6][kkS] = vb4.z; Vs[dqS + 7][kkS] = vb4.w;
        }
        __syncthreads();
#pragma unroll
        for (int ki = 0; ki < 2; ++ki) {
            float4 vv[4], sv[4];
#pragma unroll
            for (int jd = 0; jd < 4; ++jd)
                vv[jd] = *(const float4*)&Vs[dt * 4 + jd][(kg << 3) | (ki << 2)];
#pragma unroll
            for (int i = 0; i < 4; ++i) {
                const int q = qt * 4 + i;
                sv[i] = *(const float4*)&ss[q * 512 + c * 128 + (((kg ^ q) << 3) | (ki << 2))];
            }
#pragma unroll
            for (int i = 0; i < 4; ++i)
#pragma unroll
                for (int jd = 0; jd < 4; ++jd)
                    acc[i][jd] = fmaf(sv[i].x, vv[jd].x, fmaf(sv[i].y, vv[jd].y,
                                 fmaf(sv[i].z, vv[jd].z, fmaf(sv[i].w, vv[jd].w, acc[i][jd]))));
        }
    }
    // kg-reduction: partials[kg][q][d] reuse ss (exactly 16*512 floats).
    // b128 writes: banks = dt*4.. -> every bank gets exactly 8x4B (min, even).
    __syncthreads();
#pragma unroll
    for (int i = 0; i < 4; ++i)
        *(float4*)&ss[kg * 512 + (qt * 4 + i) * 32 + dt * 4] =
            make_float4(acc[i][0], acc[i][1], acc[i][2], acc[i][3]);
    __syncthreads();
    {
        const int qr = t >> 5, dr = t & 31;   // reads: bank = dr -> 2-way (free)
        float r = 0.f;
#pragma unroll
        for (int kg2 = 0; kg2 < 16; ++kg2) r += ss[kg2 * 512 + qr * 32 + dr];
        ctx[(b * LL + q0 + qr) * DD + h * DHH + dr] = r;
    }
}

// K3: output projection. Block = 4 rows (512 blocks); thread = 1 row x 4 cols.
__global__ __launch_bounds__(256) void outproj_kernel(const float* __restrict__ ctx,
    const float* __restrict__ Wo, const float* __restrict__ bo,
    float* __restrict__ out) {
    __shared__ float xs[4][DD];
    const int r0 = blockIdx.x * 4;
    const int t = threadIdx.x;
    const int rg = t >> 6;
    const int c0 = (t & 63) * 4;
    ((float4*)&xs[0][0])[t] = ((const float4*)(ctx + r0 * DD))[t];
    __syncthreads();
    float4 acc = *(const float4*)&bo[c0];
    for (int i0 = 0; i0 < DD; i0 += 8) {
        float4 wv[8];
#pragma unroll
        for (int j = 0; j < 8; ++j) wv[j] = *(const float4*)&Wo[(i0 + j) * DD + c0];
        const float4 x0 = *(const float4*)&xs[rg][i0];
        const float4 x1 = *(const float4*)&xs[rg][i0 + 4];
        const float* xf0 = (const float*)&x0;
        const float* xf1 = (const float*)&x1;
#pragma unroll
        for (int j = 0; j < 4; ++j) {
            acc.x = fmaf(xf0[j], wv[j].x, acc.x);
            acc.y = fmaf(xf0[j], wv[j].y, acc.y);
            acc.z = fmaf(xf0[j], wv[j].z, acc.z);
            acc.w = fmaf(xf0[j], wv[j].w, acc.w);
        }
#pragma unroll
        for (int j = 0; j < 4; ++j) {
            acc.x = fmaf(xf1[j], wv[j + 4].x, acc.x);
            acc.y = fmaf(xf1[j], wv[j + 4].y, acc.y);
            acc.z = fmaf(xf1[j], wv[j + 4].z, acc.z);
            acc.w = fmaf(xf1[j], wv[j + 4].w, acc.w);
        }
    }
    *(float4*)&out[(r0 + rg) * DD + c0] = acc;
}

extern "C" void kernel_launch(void* const* d_in, const int* in_sizes, int n_in,
                              void* d_out, int out_size, void* d_ws, size_t ws_size,
                              hipStream_t stream) {
    const float* x    = (const float*)d_in[0];
    const int* mk     = (const int*)d_in[1];   // jax bool -> int32
    const int* dist   = (const int*)d_in[2];
    const float* Wq = (const float*)d_in[3];
    const float* bq = (const float*)d_in[4];
    const float* Wk = (const float*)d_in[5];
    const float* bk = (const float*)d_in[6];
    const float* Wv = (const float*)d_in[7];
    const float* bv = (const float*)d_in[8];
    const float* Wo = (const float*)d_in[9];
    const float* bo = (const float*)d_in[10];
    const float* rel_table = (const float*)d_in[11];
    const float* uvec = (const float*)d_in[12];
    const float* vvec = (const float*)d_in[13];

    float* out  = (float*)d_out;                 // (B,L,D)
    float* attn = out + BB * LL * DD;            // (B,H,L,L)

    float* Qu = (float*)d_ws;                    // q/sqrt(dh) + u
    float* Qv = Qu + BB * LL * DD;               // q/sqrt(dh) + v
    float* KT = Qv + BB * LL * DD;               // [B][H][DH][L]
    float* V  = KT + BB * LL * DD;               // [B][L][D]
    float* C  = V + BB * LL * DD;                // ctx (B,L,D); 10.5 MB ws total

    qkv_kernel<<<3 * 256, 256, 0, stream>>>(x, Wq, bq, Wk, bk, Wv, bv, uvec, vvec,
                                            Qu, Qv, KT, V);
    scores_ctx_kernel<<<BB * (LL / 16) * HH, 512, 0, stream>>>(Qu, Qv, KT, rel_table,
                                                               mk, dist, V, attn, C);
    outproj_kernel<<<BB * LL / 4, 256, 0, stream>>>(C, Wo, bo, out);
}

// Round 2
// 170.103 us; speedup vs baseline: 2.6132x; 2.6132x over previous
//
#include <hip/hip_runtime.h>
#include <math.h>

#define BB 4
#define LL 512
#define DD 256
#define HH 8
#define DHH 32
#define NB 12  // BUCKETS + 1 (row 11 is the zero padding row)

// K1: QKV projections (8-row tiles, 768 blocks = 3 blocks/CU).
// Thread = 2 rows x 4 cols. mat0 writes Qu=q/sqrt(dh)+u, Qv=q/sqrt(dh)+v;
// mat1 writes KT[b][h][d][k]; mat2 writes V[b][k][d].
__global__ __launch_bounds__(256) void qkv_kernel(const float* __restrict__ x,
    const float* __restrict__ Wq, const float* __restrict__ bq,
    const float* __restrict__ Wk, const float* __restrict__ bk,
    const float* __restrict__ Wv, const float* __restrict__ bv,
    const float* __restrict__ uvec, const float* __restrict__ vvec,
    float* __restrict__ Qu, float* __restrict__ Qv,
    float* __restrict__ KT, float* __restrict__ V) {
    __shared__ float xs[8][DD];
    const int mat = blockIdx.x >> 8;          // 0=Q, 1=K, 2=V
    const int r0 = (blockIdx.x & 255) * 8;
    const int t = threadIdx.x;
    const int cg = t & 63, rg = t >> 6;
    const int c0 = cg * 4;
    {
        const float4* xg = (const float4*)(x + r0 * DD);
        float4* xsv = (float4*)&xs[0][0];
        xsv[t] = xg[t];
        xsv[t + 256] = xg[t + 256];
    }
    __syncthreads();
    const float* W    = (mat == 0) ? Wq : (mat == 1) ? Wk : Wv;
    const float* bias = (mat == 0) ? bq : (mat == 1) ? bk : bv;
    float acc[2][4];
#pragma unroll
    for (int r = 0; r < 2; ++r)
#pragma unroll
        for (int c = 0; c < 4; ++c) acc[r][c] = bias[c0 + c];
    for (int i0 = 0; i0 < DD; i0 += 4) {
        float4 wv4[4], xv4[2];
#pragma unroll
        for (int j = 0; j < 4; ++j) wv4[j] = *(const float4*)&W[(i0 + j) * DD + c0];
#pragma unroll
        for (int r = 0; r < 2; ++r) xv4[r] = *(const float4*)&xs[rg * 2 + r][i0];
        const float* wf = (const float*)wv4;
        const float* xf = (const float*)xv4;
#pragma unroll
        for (int r = 0; r < 2; ++r)
#pragma unroll
            for (int j = 0; j < 4; ++j)
#pragma unroll
                for (int c = 0; c < 4; ++c)
                    acc[r][c] = fmaf(xf[r * 4 + j], wf[j * 4 + c], acc[r][c]);
    }
    if (mat == 0) {
        const float s = 0.17677669529663687f;  // 1/sqrt(DH)
        const float4 u4 = *(const float4*)&uvec[c0];
        const float4 v4 = *(const float4*)&vvec[c0];
#pragma unroll
        for (int r = 0; r < 2; ++r) {
            const int row = r0 + rg * 2 + r;
            float4 q = make_float4(acc[r][0] * s, acc[r][1] * s, acc[r][2] * s, acc[r][3] * s);
            *(float4*)&Qu[row * DD + c0] = make_float4(q.x + u4.x, q.y + u4.y, q.z + u4.z, q.w + u4.w);
            *(float4*)&Qv[row * DD + c0] = make_float4(q.x + v4.x, q.y + v4.y, q.z + v4.z, q.w + v4.w);
        }
    } else if (mat == 1) {
        const int b = r0 >> 9;
        const int kb = (r0 & 511) + rg * 2;
#pragma unroll
        for (int c = 0; c < 4; ++c) {
            const int col = c0 + c;
            const int h = col >> 5, dd = col & 31;
            float* p = KT + ((long)((b * HH + h) * DHH + dd)) * LL + kb;
            p[0] = acc[0][c];
            p[1] = acc[1][c];
        }
    } else {
#pragma unroll
        for (int r = 0; r < 2; ++r)
            *(float4*)&V[(r0 + rg * 2 + r) * DD + c0] =
                make_float4(acc[r][0], acc[r][1], acc[r][2], acc[r][3]);
    }
}

// K2: fused rel-P + scores + softmax + attn write + ctx.
// Phase A: round-0 structure (s-loop OUTER, only 8 scores + 8 kv float4 live
// -> fits 64 VGPR, no spill; the round-1 d8-outer restructure spilled ~1.6KB
// per thread: FETCH 43->389MB). Per-s epilogue writes attn + swizzled ss.
// ss swizzle: row q, chunk c, octet o at ss[q*512 + c*128 + ((o^(q>>2))*8|h4)].
// Read side (phase B) fixes i => the 4 q-rows differ only in q>>2=qt, so
// (kg^qt) spans 4 distinct bank quads -> conflict-free (round-1's o^q was a
// no-op on bank bits: q's low 2 bits constant per instruction -> 4-way).
// Write side: XOR with a row-constant is bijective per 128-chunk -> uniform.
// Phase B: thread = (qt,dt,kg) = 4 q-tiles x 8 d-tiles x 16 k-octets; 4qx4d
// register tile per 8-k octet: 16 ds_read_b128 feed 128 FMA per chunk
// (64 b128/thread total vs round-0's 256 -> 4x less LDS-pipe pressure; the
// round-0 kernel was LDS-throughput-bound: 256 b128 * 12cy ~= 41us).
// Peak live regs in phase B inner: acc16+sv16+vv4 ~= 45. c-loop pinned
// no-unroll so the scheduler can't hoist 4 chunks of loads into flight.
// kg-partials reduced via LDS reusing dead ss (bank-uniform both sides).
__global__ __launch_bounds__(512, 4) void scores_ctx_kernel(const float* __restrict__ Qu,
    const float* __restrict__ Qv, const float* __restrict__ KT,
    const float* __restrict__ rel_table, const int* __restrict__ mask,
    const int* __restrict__ dist, const float* __restrict__ V,
    float* __restrict__ attn, float* __restrict__ ctx) {
    __shared__ float Qs[16][DHH];
    __shared__ float Ps[16][NB];
    __shared__ float ss[16 * 512];      // swizzled S tile (32KB); preamble aliases Qv8/rels; epilogue aliases partials
    __shared__ float Vs[DHH][133];      // V chunk, transposed [d][k] (+pad 133: gcd(5,32)=1)
    const int blk = blockIdx.x;         // ((b*32 + qt16)*8 + h)
    const int h = blk & 7;
    const int rest = blk >> 3;
    const int qt16 = rest & 31;
    const int b = rest >> 5;
    const int q0 = qt16 * 16;
    const int t = threadIdx.x;
    const int w = t >> 6, l = t & 63;

    float* Qv8  = ss;                   // [16][32]  (dead after Ps compute)
    float* rels = ss + 512;             // [12][33]  (dead after Ps compute)

    {
        const int r = t >> 5, c = t & 31;
        Qs[r][c]          = Qu[(b * LL + q0 + r) * DD + h * DHH + c];
        Qv8[r * DHH + c]  = Qv[(b * LL + q0 + r) * DD + h * DHH + c];
    }
    if (t < NB * DHH) {
        rels[(t >> 5) * 33 + (t & 31)] = rel_table[(t >> 5) * DD + h * DHH + (t & 31)];
    }
    __syncthreads();
    if (t < 16 * NB) {                  // Ps[r][bk] = dot32(Qv8[r], rels[bk])
        const int bk = t >> 4, r = t & 15;
        float a = 0.f;
#pragma unroll
        for (int d = 0; d < DHH; ++d) a = fmaf(Qv8[r * DHH + d], rels[bk * 33 + d], a);
        Ps[r][bk] = a;
    }
    __syncthreads();                    // after this barrier Qv8/rels are dead; ss is writable

    // ---- Phase A: scores + softmax for this wave's 2 q rows (round-0 form) ----
    const int r0 = 2 * w;
    const long kbase = (long)(b * HH + h) * DHH * LL;
    float e0[2][4], e1[2][4];
    float sum0 = 0.f, sum1 = 0.f;
#pragma unroll
    for (int s = 0; s < 2; ++s) {
        const int k0 = 4 * l + 256 * s;
        const int4 dx0 = *(const int4*)&dist[(b * LL + q0 + r0) * LL + k0];
        const int4 dx1 = *(const int4*)&dist[(b * LL + q0 + r0 + 1) * LL + k0];
        const int4 mx0 = *(const int4*)&mask[(b * LL + q0 + r0) * LL + k0];
        const int4 mx1 = *(const int4*)&mask[(b * LL + q0 + r0 + 1) * LL + k0];
        float s0[4], s1[4];
        s0[0] = Ps[r0][dx0.x]; s0[1] = Ps[r0][dx0.y]; s0[2] = Ps[r0][dx0.z]; s0[3] = Ps[r0][dx0.w];
        s1[0] = Ps[r0 + 1][dx1.x]; s1[1] = Ps[r0 + 1][dx1.y]; s1[2] = Ps[r0 + 1][dx1.z]; s1[3] = Ps[r0 + 1][dx1.w];
#pragma unroll
        for (int d8 = 0; d8 < DHH; d8 += 8) {
            float4 kv[8];                        // 8 loads in flight
#pragma unroll
            for (int j = 0; j < 8; ++j)
                kv[j] = *(const float4*)&KT[kbase + (long)(d8 + j) * LL + k0];
            const float4 q0a = *(const float4*)&Qs[r0][d8];
            const float4 q0b = *(const float4*)&Qs[r0][d8 + 4];
            const float4 q1a = *(const float4*)&Qs[r0 + 1][d8];
            const float4 q1b = *(const float4*)&Qs[r0 + 1][d8 + 4];
            const float* qa0 = (const float*)&q0a;
            const float* qb0 = (const float*)&q0b;
            const float* qa1 = (const float*)&q1a;
            const float* qb1 = (const float*)&q1b;
#pragma unroll
            for (int j = 0; j < 4; ++j) {
                s0[0] = fmaf(qa0[j], kv[j].x, s0[0]);
                s0[1] = fmaf(qa0[j], kv[j].y, s0[1]);
                s0[2] = fmaf(qa0[j], kv[j].z, s0[2]);
                s0[3] = fmaf(qa0[j], kv[j].w, s0[3]);
                s1[0] = fmaf(qa1[j], kv[j].x, s1[0]);
                s1[1] = fmaf(qa1[j], kv[j].y, s1[1]);
                s1[2] = fmaf(qa1[j], kv[j].z, s1[2]);
                s1[3] = fmaf(qa1[j], kv[j].w, s1[3]);
            }
#pragma unroll
            for (int j = 0; j < 4; ++j) {
                s0[0] = fmaf(qb0[j], kv[j + 4].x, s0[0]);
                s0[1] = fmaf(qb0[j], kv[j + 4].y, s0[1]);
                s0[2] = fmaf(qb0[j], kv[j + 4].z, s0[2]);
                s0[3] = fmaf(qb0[j], kv[j + 4].w, s0[3]);
                s1[0] = fmaf(qb1[j], kv[j + 4].x, s1[0]);
                s1[1] = fmaf(qb1[j], kv[j + 4].y, s1[1]);
                s1[2] = fmaf(qb1[j], kv[j + 4].z, s1[2]);
                s1[3] = fmaf(qb1[j], kv[j + 4].w, s1[3]);
            }
        }
        e0[s][0] = mx0.x ? 0.f : __expf(s0[0]);
        e0[s][1] = mx0.y ? 0.f : __expf(s0[1]);
        e0[s][2] = mx0.z ? 0.f : __expf(s0[2]);
        e0[s][3] = mx0.w ? 0.f : __expf(s0[3]);
        e1[s][0] = mx1.x ? 0.f : __expf(s1[0]);
        e1[s][1] = mx1.y ? 0.f : __expf(s1[1]);
        e1[s][2] = mx1.z ? 0.f : __expf(s1[2]);
        e1[s][3] = mx1.w ? 0.f : __expf(s1[3]);
        sum0 += (e0[s][0] + e0[s][1]) + (e0[s][2] + e0[s][3]);
        sum1 += (e1[s][0] + e1[s][1]) + (e1[s][2] + e1[s][3]);
    }
    for (int off = 32; off > 0; off >>= 1) {
        sum0 += __shfl_xor(sum0, off);
        sum1 += __shfl_xor(sum1, off);
    }
    const float inv0 = 1.0f / sum0, inv1 = 1.0f / sum1;
    float* a0 = attn + ((long)(b * HH + h) * LL + q0 + r0) * LL;
    float* a1 = a0 + LL;
#pragma unroll
    for (int s = 0; s < 2; ++s) {
        const int k0 = 4 * l + 256 * s;
        const int ch = k0 >> 7;
        const int oct = (k0 & 127) >> 3;
        const int h4 = k0 & 4;
        const float4 o0 = make_float4(e0[s][0] * inv0, e0[s][1] * inv0, e0[s][2] * inv0, e0[s][3] * inv0);
        const float4 o1 = make_float4(e1[s][0] * inv1, e1[s][1] * inv1, e1[s][2] * inv1, e1[s][3] * inv1);
        *(float4*)&a0[k0] = o0;
        *(float4*)&a1[k0] = o1;
        *(float4*)&ss[r0 * 512 + ch * 128 + (((oct ^ (r0 >> 2)) << 3) | h4)] = o0;
        *(float4*)&ss[(r0 + 1) * 512 + ch * 128 + (((oct ^ ((r0 + 1) >> 2)) << 3) | h4)] = o1;
    }

    // ---- Phase B: ctx via 4q x 4d register tiles over LDS-staged V chunks ----
    const int qt = t & 3;               // q-tile (rows 4qt..4qt+3); == q>>2 for its rows
    const int dt = (t >> 2) & 7;        // d-tile (cols 4dt..4dt+3)
    const int kg = t >> 5;              // k-octet within chunk (0..15)
    const int kkS = t >> 2;             // staging row 0..127
    const int dqS = (t & 3) * 8;        // staging d-group of 8
    float acc[4][4];
#pragma unroll
    for (int i = 0; i < 4; ++i)
#pragma unroll
        for (int jd = 0; jd < 4; ++jd) acc[i][jd] = 0.f;
#pragma unroll 1
    for (int c = 0; c < 4; ++c) {
        __syncthreads();                // prev compute done (and ss ready at c=0)
        {   // stage V[b][c*128+kk][h*32+dq..dq+7] -> Vs[d][kk] (transposed)
            const float* vg = V + ((long)(b * LL + c * 128 + kkS)) * DD + h * DHH + dqS;
            const float4 va = *(const float4*)&vg[0];
            const float4 vb4 = *(const float4*)&vg[4];
            Vs[dqS + 0][kkS] = va.x;  Vs[dqS + 1][kkS] = va.y;
            Vs[dqS + 2][kkS] = va.z;  Vs[dqS + 3][kkS] = va.w;
            Vs[dqS + 4][kkS] = vb4.x; Vs[dqS + 5][kkS] = vb4.y;
            Vs[dqS + 6][kkS] = vb4.z; Vs[dqS + 7][kkS] = vb4.w;
        }
        __syncthreads();
#pragma unroll
        for (int ki = 0; ki < 2; ++ki) {
            float4 sv[4];
#pragma unroll
            for (int i = 0; i < 4; ++i)
                sv[i] = *(const float4*)&ss[(qt * 4 + i) * 512 + c * 128 + (((kg ^ qt) << 3) | (ki << 2))];
#pragma unroll
            for (int jd = 0; jd < 4; ++jd) {
                const float4 vv = *(const float4*)&Vs[dt * 4 + jd][(kg << 3) | (ki << 2)];
#pragma unroll
                for (int i = 0; i < 4; ++i)
                    acc[i][jd] = fmaf(sv[i].x, vv.x, fmaf(sv[i].y, vv.y,
                                 fmaf(sv[i].z, vv.z, fmaf(sv[i].w, vv.w, acc[i][jd]))));
            }
        }
    }
    // kg-reduction: partials[kg][q][d] reuse ss (exactly 16*512 floats).
    // b128 writes: start bank = dt*4 -> 8 starts x 8 lanes -> 8 words/bank (uniform).
    __syncthreads();
#pragma unroll
    for (int i = 0; i < 4; ++i)
        *(float4*)&ss[kg * 512 + (qt * 4 + i) * 32 + dt * 4] =
            make_float4(acc[i][0], acc[i][1], acc[i][2], acc[i][3]);
    __syncthreads();
    {
        const int qr = t >> 5, dr = t & 31;   // reads: bank = dr -> 2-way (free)
        float r = 0.f;
#pragma unroll
        for (int kg2 = 0; kg2 < 16; ++kg2) r += ss[kg2 * 512 + qr * 32 + dr];
        ctx[(b * LL + q0 + qr) * DD + h * DHH + dr] = r;
    }
}

// K3: output projection. Block = 4 rows (512 blocks); thread = 1 row x 4 cols.
__global__ __launch_bounds__(256) void outproj_kernel(const float* __restrict__ ctx,
    const float* __restrict__ Wo, const float* __restrict__ bo,
    float* __restrict__ out) {
    __shared__ float xs[4][DD];
    const int r0 = blockIdx.x * 4;
    const int t = threadIdx.x;
    const int rg = t >> 6;
    const int c0 = (t & 63) * 4;
    ((float4*)&xs[0][0])[t] = ((const float4*)(ctx + r0 * DD))[t];
    __syncthreads();
    float4 acc = *(const float4*)&bo[c0];
    for (int i0 = 0; i0 < DD; i0 += 8) {
        float4 wv[8];
#pragma unroll
        for (int j = 0; j < 8; ++j) wv[j] = *(const float4*)&Wo[(i0 + j) * DD + c0];
        const float4 x0 = *(const float4*)&xs[rg][i0];
        const float4 x1 = *(const float4*)&xs[rg][i0 + 4];
        const float* xf0 = (const float*)&x0;
        const float* xf1 = (const float*)&x1;
#pragma unroll
        for (int j = 0; j < 4; ++j) {
            acc.x = fmaf(xf0[j], wv[j].x, acc.x);
            acc.y = fmaf(xf0[j], wv[j].y, acc.y);
            acc.z = fmaf(xf0[j], wv[j].z, acc.z);
            acc.w = fmaf(xf0[j], wv[j].w, acc.w);
        }
#pragma unroll
        for (int j = 0; j < 4; ++j) {
            acc.x = fmaf(xf1[j], wv[j + 4].x, acc.x);
            acc.y = fmaf(xf1[j], wv[j + 4].y, acc.y);
            acc.z = fmaf(xf1[j], wv[j + 4].z, acc.z);
            acc.w = fmaf(xf1[j], wv[j + 4].w, acc.w);
        }
    }
    *(float4*)&out[(r0 + rg) * DD + c0] = acc;
}

extern "C" void kernel_launch(void* const* d_in, const int* in_sizes, int n_in,
                              void* d_out, int out_size, void* d_ws, size_t ws_size,
                              hipStream_t stream) {
    const float* x    = (const float*)d_in[0];
    const int* mk     = (const int*)d_in[1];   // jax bool -> int32
    const int* dist   = (const int*)d_in[2];
    const float* Wq = (const float*)d_in[3];
    const float* bq = (const float*)d_in[4];
    const float* Wk = (const float*)d_in[5];
    const float* bk = (const float*)d_in[6];
    const float* Wv = (const float*)d_in[7];
    const float* bv = (const float*)d_in[8];
    const float* Wo = (const float*)d_in[9];
    const float* bo = (const float*)d_in[10];
    const float* rel_table = (const float*)d_in[11];
    const float* uvec = (const float*)d_in[12];
    const float* vvec = (const float*)d_in[13];

    float* out  = (float*)d_out;                 // (B,L,D)
    float* attn = out + BB * LL * DD;            // (B,H,L,L)

    float* Qu = (float*)d_ws;                    // q/sqrt(dh) + u
    float* Qv = Qu + BB * LL * DD;               // q/sqrt(dh) + v
    float* KT = Qv + BB * LL * DD;               // [B][H][DH][L]
    float* V  = KT + BB * LL * DD;               // [B][L][D]
    float* C  = V + BB * LL * DD;                // ctx (B,L,D); 10.5 MB ws total

    qkv_kernel<<<3 * 256, 256, 0, stream>>>(x, Wq, bq, Wk, bk, Wv, bv, uvec, vvec,
                                            Qu, Qv, KT, V);
    scores_ctx_kernel<<<BB * (LL / 16) * HH, 512, 0, stream>>>(Qu, Qv, KT, rel_table,
                                                               mk, dist, V, attn, C);
    outproj_kernel<<<BB * LL / 4, 256, 0, stream>>>(C, Wo, bo, out);
}